// Round 4
// baseline (926.607 us; speedup 1.0000x reference)
//
#include <hip/hip_runtime.h>
#include <hip/hip_fp16.h>

#define N_NODES 30000
#define N_EDGES 240000
#define EMB     300
#define NPAD    30080   // 235 * 128
#define K1      320     // padded EMB (gemm1 K, agg cols, fp16)
#define NP1     640     // padded 2*EMB (gemm1 out cols = gemm2 K)
#define NP2     384     // gemm2 padded col count / h2 fp16 row stride
#define HSH     304     // h row stride in fp16 elements
#define LAYERS  5

typedef _Float16 half8 __attribute__((ext_vector_type(8)));
typedef __attribute__((ext_vector_type(4))) float floatx4;
typedef float v2f __attribute__((ext_vector_type(2)));

// async 16B global->LDS (per-lane gptr, LDS dest = wave-uniform base + lane*16)
__device__ __forceinline__ void gload16(const void* g, void* l) {
  __builtin_amdgcn_global_load_lds(
      (const __attribute__((address_space(1))) unsigned int*)g,
      (__attribute__((address_space(3))) unsigned int*)l, 16, 0, 0);
}

__device__ __forceinline__ v2f h2f(__half2 h) {
  float2 f = __half22float2(h);
  v2f r; r.x = f.x; r.y = f.y; return r;
}

// ---------------- fused prep: zero deg/stat, convert weights, embed ----------------
__global__ __launch_bounds__(256)
void prep_kernel(const float* __restrict__ W1, const float* __restrict__ W2,
                 const float* __restrict__ b1, const float* __restrict__ b2,
                 const int* __restrict__ x, const float* __restrict__ emb1,
                 const float* __restrict__ emb2,
                 __half* __restrict__ w1t, __half* __restrict__ w2t,
                 float* __restrict__ b1p, float* __restrict__ b2p,
                 __half* __restrict__ h, int* __restrict__ deg,
                 float* __restrict__ stat) {
  const int Z0 = N_NODES;                       // deg zero
  const int Z1 = Z0 + LAYERS * 2 * EMB;         // stat zero
  const int R0 = Z1 + LAYERS * NP1 * K1;        // w1t
  const int R1 = R0 + LAYERS * NP2 * NP1;       // w2t
  const int R2 = R1 + LAYERS * NP1;             // b1p
  const int R3 = R2 + LAYERS * NP2;             // b2p
  const int R4 = R3 + N_NODES * HSH;            // embed
  for (int i = blockIdx.x * 256 + threadIdx.x; i < R4; i += gridDim.x * 256) {
    if (i < Z0) {
      deg[i] = 0;
    } else if (i < Z1) {
      stat[i - Z0] = 0.f;
    } else if (i < R0) {
      int idx = i - Z1;
      int l = idx / (NP1 * K1);
      int rem = idx % (NP1 * K1);
      int n = rem / K1, k = rem % K1;
      float v = (n < 2 * EMB && k < EMB)
                    ? W1[(size_t)l * EMB * 2 * EMB + (size_t)k * 2 * EMB + n] : 0.f;
      w1t[idx] = __float2half(v);
    } else if (i < R1) {
      int idx = i - R0;
      int l = idx / (NP2 * NP1);
      int rem = idx % (NP2 * NP1);
      int n = rem / NP1, k = rem % NP1;
      float v = (n < EMB && k < 2 * EMB)
                    ? W2[(size_t)l * 2 * EMB * EMB + (size_t)k * EMB + n] : 0.f;
      w2t[idx] = __float2half(v);
    } else if (i < R2) {
      int idx = i - R1;
      int l = idx / NP1, j = idx % NP1;
      b1p[idx] = (j < 2 * EMB) ? b1[l * 2 * EMB + j] : 0.f;
    } else if (i < R3) {
      int idx = i - R2;
      int l = idx / NP2, j = idx % NP2;
      b2p[idx] = (j < EMB) ? b2[l * EMB + j] : 0.f;
    } else {
      int j = i - R3;
      int node = j / HSH, c = j - node * HSH;
      if (c < EMB) {
        int t0 = x[node * 2], t1 = x[node * 2 + 1];
        h[(size_t)node * HSH + c] = __float2half(emb1[t0 * EMB + c] + emb2[t1 * EMB + c]);
      }
    }
  }
}

// ---------------- CSR build ----------------
__global__ void count_kernel(const int* __restrict__ ei, int* __restrict__ deg) {
  int e = blockIdx.x * 256 + threadIdx.x;
  if (e < N_EDGES) atomicAdd(&deg[ei[N_EDGES + e]], 1);
}

#define SCH 30   // 1024 * 30 = 30720 >= N_NODES
__global__ __launch_bounds__(1024)
void scan_kernel(const int* __restrict__ deg, int* __restrict__ row_ptr,
                 int* __restrict__ curs) {
  int tid = threadIdx.x;
  int base = tid * SCH;
  int loc[SCH];
  int s = 0;
#pragma unroll
  for (int j = 0; j < SCH; ++j) {
    int i = base + j;
    int v = (i < N_NODES) ? deg[i] : 0;
    loc[j] = s;          // exclusive prefix within chunk
    s += v;
  }
  int lane = tid & 63, wv = tid >> 6;
  int x = s;
#pragma unroll
  for (int o = 1; o < 64; o <<= 1) {
    int y = __shfl_up(x, o, 64);
    if (lane >= o) x += y;
  }
  __shared__ int wsum[16], woff[16];
  if (lane == 63) wsum[wv] = x;
  __syncthreads();
  if (tid == 0) {
    int acc = 0;
    for (int w = 0; w < 16; ++w) { woff[w] = acc; acc += wsum[w]; }
    row_ptr[N_NODES] = acc;
  }
  __syncthreads();
  int excl = woff[wv] + x - s;    // exclusive prefix of this thread's chunk
#pragma unroll
  for (int j = 0; j < SCH; ++j) {
    int i = base + j;
    if (i < N_NODES) { int val = excl + loc[j]; row_ptr[i] = val; curs[i] = val; }
  }
}

__global__ void fill_kernel(const int* __restrict__ ei, const int* __restrict__ ea,
                            int* __restrict__ cursor, int* __restrict__ ebuf) {
  int e = blockIdx.x * 256 + threadIdx.x;
  if (e >= N_EDGES) return;
  int d = ei[N_EDGES + e];
  int pos = atomicAdd(&cursor[d], 1);
  ebuf[pos] = ei[e] * 32 + (ea[2 * e] * 3 + ea[2 * e + 1]);  // src*32 + combo
}

// ---------------- aggregation: fp16 gather-sum, 8x edge unroll ----------------
// v5: combo back to fp16 (11KB LDS -> max residency; R3 showed occupancy
// matters more than VALU) + 8-edge unroll with 24 explicit live loads for
// real memory-level parallelism (R2/R3 VGPR=28-36 proved the compiler was
// recycling registers and serializing the "batched" gathers).
__global__ __launch_bounds__(256)
void aggregate_kernel(const __half* __restrict__ h,
                      const int* __restrict__ row_ptr,
                      const int* __restrict__ ebuf,
                      const float* __restrict__ e1,   // [6,300] this layer
                      const float* __restrict__ e2,   // [3,300] this layer
                      __half* __restrict__ agg) {
  __shared__ __half2 combo[18][150];   // 10.8 KB
  int tid = threadIdx.x;
  for (int idx = tid; idx < 18 * 150; idx += 256) {
    int t = idx / 150, p = idx % 150;
    int a0 = t / 3, a1 = t % 3;
    combo[t][p] = __floats2half2_rn(e1[a0 * EMB + 2 * p]     + e2[a1 * EMB + 2 * p],
                                    e1[a0 * EMB + 2 * p + 1] + e2[a1 * EMB + 2 * p + 1]);
  }
  __syncthreads();
  int wave = tid >> 6, lane = tid & 63;
  int node = blockIdx.x * 4 + wave;
  v2f A0 = {0.f, 0.f}, A1 = {0.f, 0.f}, A2 = {0.f, 0.f};
  v2f B0 = {0.f, 0.f}, B1 = {0.f, 0.f}, B2 = {0.f, 0.f};
  int p2 = lane + 128;
  bool has2 = (p2 < 150);
  if (node < N_NODES) {
    int ebeg = row_ptr[node], eend = row_ptr[node + 1];
    int e = ebeg;
    // ---- 8-edge unrolled main loop: issue ALL 24 gathers, then accumulate ----
    for (; e + 8 <= eend; e += 8) {
      int v[8];
#pragma unroll
      for (int j = 0; j < 8; ++j) v[j] = ebuf[e + j];
      const __half2* hp[8];
#pragma unroll
      for (int j = 0; j < 8; ++j) hp[j] = (const __half2*)(h + (size_t)(v[j] >> 5) * HSH);
      __half2 x0[8], x1[8], x2[8];
#pragma unroll
      for (int j = 0; j < 8; ++j) { x0[j] = hp[j][lane]; x1[j] = hp[j][lane + 64]; }
      if (has2) {
#pragma unroll
        for (int j = 0; j < 8; ++j) x2[j] = hp[j][p2];
      }
#pragma unroll
      for (int j = 0; j < 8; ++j) {
        int tc = v[j] & 31;
        if (j & 1) {
          B0 += h2f(x0[j]) + h2f(combo[tc][lane]);
          B1 += h2f(x1[j]) + h2f(combo[tc][lane + 64]);
          if (has2) B2 += h2f(x2[j]) + h2f(combo[tc][p2]);
        } else {
          A0 += h2f(x0[j]) + h2f(combo[tc][lane]);
          A1 += h2f(x1[j]) + h2f(combo[tc][lane + 64]);
          if (has2) A2 += h2f(x2[j]) + h2f(combo[tc][p2]);
        }
      }
    }
    // ---- 2-edge pairs ----
    for (; e + 2 <= eend; e += 2) {
      int v0 = ebuf[e], v1 = ebuf[e + 1];
      const __half2* hp0 = (const __half2*)(h + (size_t)(v0 >> 5) * HSH);
      const __half2* hp1 = (const __half2*)(h + (size_t)(v1 >> 5) * HSH);
      int t0 = v0 & 31, t1 = v1 & 31;
      __half2 x00 = hp0[lane], x01 = hp0[lane + 64];
      __half2 x10 = hp1[lane], x11 = hp1[lane + 64];
      A0 += h2f(x00) + h2f(combo[t0][lane]);
      A1 += h2f(x01) + h2f(combo[t0][lane + 64]);
      B0 += h2f(x10) + h2f(combo[t1][lane]);
      B1 += h2f(x11) + h2f(combo[t1][lane + 64]);
      if (has2) {
        A2 += h2f(hp0[p2]) + h2f(combo[t0][p2]);
        B2 += h2f(hp1[p2]) + h2f(combo[t1][p2]);
      }
    }
    // ---- tail edge (if odd count) + self loop ----
    for (; e <= eend; ++e) {
      int s, t;
      if (e < eend) { int v = ebuf[e]; s = v >> 5; t = v & 31; }
      else          { s = node;        t = 4 * 3 + 0; }
      const __half2* hp = (const __half2*)(h + (size_t)s * HSH);
      A0 += h2f(hp[lane])      + h2f(combo[t][lane]);
      A1 += h2f(hp[lane + 64]) + h2f(combo[t][lane + 64]);
      if (has2) A2 += h2f(hp[p2]) + h2f(combo[t][p2]);
    }
  }
  A0 += B0; A1 += B1; A2 += B2;
  __half2* op = (__half2*)(agg + (size_t)node * K1);
  op[lane]      = __floats2half2_rn(A0.x, A0.y);
  op[lane + 64] = __floats2half2_rn(A1.x, A1.y);
  if (p2 < 160) op[p2] = has2 ? __floats2half2_rn(A2.x, A2.y)
                              : __floats2half2_rn(0.f, 0.f);   // zero K-pad cols
}

// ---------------- fp16 MFMA GEMM: C = act(A @ B^T + bias) ----------------
// v4: B fragments DIRECT global->VGPR (ping-pong prefetch), A only in LDS.
// Rationale (R3 model): LDS is per-CU shared (128B/clk) while MFMA pipes are
// per-SIMD; with A+B both in LDS each wave-Kstep read 8KB for 78cyc of MFMA
// -> LDS-throughput-bound at ~30% MfmaUtil. B is a tiny L2-hot weight matrix
// (each row of Bt is read by all 235 row-blocks), so bf loads come from L2.
// LDS traffic halves -> MfmaUtil cap ~doubles.
// vmcnt ledger (behind A(t) in issue order): A(t+1)=2, bf(t)=4, A(t+2)=2,
// bf(t+1)=4 -> vmcnt(12) main; t=nT-2: 10; t=nT-1: 4. Compiler inserts its
// own (conservative, safe) counted waits for the bf loads it tracks.
#define KSTEP(T, CUR, BFU, BFP, STG, PREF, W) do {                              \
    if (STG) { int nb_ = (CUR) + 2; if (nb_ >= 3) nb_ -= 3;                     \
      int kc_ = ((T) + 2) << 5;                                                 \
      gload16(ga0 + kc_, &As[nb_][soff]);                                       \
      gload16(ga1 + kc_, &As[nb_][soff + 2048]); }                              \
    if (PREF) { int kp_ = ((T) + 1) << 5;                                       \
      BFP[0] = *(const half8*)(gb0 + kp_);                                      \
      BFP[1] = *(const half8*)(gb1 + kp_);                                      \
      BFP[2] = *(const half8*)(gb2 + kp_);                                      \
      BFP[3] = *(const half8*)(gb3 + kp_); }                                    \
    asm volatile("s_waitcnt vmcnt(%0)" :: "i"(W) : "memory");                   \
    asm volatile("s_barrier" ::: "memory");                                     \
    half8 af0 = *(const half8*)&As[CUR][aoff];                                  \
    half8 af1 = *(const half8*)&As[CUR][aoff + 512];                            \
    half8 af2 = *(const half8*)&As[CUR][aoff + 1024];                           \
    half8 af3 = *(const half8*)&As[CUR][aoff + 1536];                           \
    asm volatile("s_waitcnt lgkmcnt(0)" ::: "memory");                          \
    __builtin_amdgcn_sched_barrier(0);                                          \
    asm volatile("s_barrier" ::: "memory");                                     \
    acc[0][0] = __builtin_amdgcn_mfma_f32_16x16x32_f16(af0, BFU[0], acc[0][0], 0, 0, 0); \
    acc[0][1] = __builtin_amdgcn_mfma_f32_16x16x32_f16(af0, BFU[1], acc[0][1], 0, 0, 0); \
    acc[0][2] = __builtin_amdgcn_mfma_f32_16x16x32_f16(af0, BFU[2], acc[0][2], 0, 0, 0); \
    acc[0][3] = __builtin_amdgcn_mfma_f32_16x16x32_f16(af0, BFU[3], acc[0][3], 0, 0, 0); \
    acc[1][0] = __builtin_amdgcn_mfma_f32_16x16x32_f16(af1, BFU[0], acc[1][0], 0, 0, 0); \
    acc[1][1] = __builtin_amdgcn_mfma_f32_16x16x32_f16(af1, BFU[1], acc[1][1], 0, 0, 0); \
    acc[1][2] = __builtin_amdgcn_mfma_f32_16x16x32_f16(af1, BFU[2], acc[1][2], 0, 0, 0); \
    acc[1][3] = __builtin_amdgcn_mfma_f32_16x16x32_f16(af1, BFU[3], acc[1][3], 0, 0, 0); \
    acc[2][0] = __builtin_amdgcn_mfma_f32_16x16x32_f16(af2, BFU[0], acc[2][0], 0, 0, 0); \
    acc[2][1] = __builtin_amdgcn_mfma_f32_16x16x32_f16(af2, BFU[1], acc[2][1], 0, 0, 0); \
    acc[2][2] = __builtin_amdgcn_mfma_f32_16x16x32_f16(af2, BFU[2], acc[2][2], 0, 0, 0); \
    acc[2][3] = __builtin_amdgcn_mfma_f32_16x16x32_f16(af2, BFU[3], acc[2][3], 0, 0, 0); \
    acc[3][0] = __builtin_amdgcn_mfma_f32_16x16x32_f16(af3, BFU[0], acc[3][0], 0, 0, 0); \
    acc[3][1] = __builtin_amdgcn_mfma_f32_16x16x32_f16(af3, BFU[1], acc[3][1], 0, 0, 0); \
    acc[3][2] = __builtin_amdgcn_mfma_f32_16x16x32_f16(af3, BFU[2], acc[3][2], 0, 0, 0); \
    acc[3][3] = __builtin_amdgcn_mfma_f32_16x16x32_f16(af3, BFU[3], acc[3][3], 0, 0, 0); \
  } while (0)

template<int RELU, int STATS>
__global__ __launch_bounds__(256, 3)
void gemm_kernel(const __half* __restrict__ A, int lda,
                 const __half* __restrict__ Bt, int ldb,
                 const float* __restrict__ bias,
                 __half* __restrict__ C, int ldc, int K,
                 float* __restrict__ stats) {
  __shared__ _Float16 As[3][128 * 32];   // A-only ring, 24 KB
  __shared__ float cs[128], cq[128];
  int tid = threadIdx.x;
  int wave = tid >> 6, lane = tid & 63;
  int wm = wave >> 1, wn = wave & 1;
  int row0 = blockIdx.y * 128, col0 = blockIdx.x * 128;   // x = column tile (fast)
  int sr = tid >> 2;                                   // staging row
  int scg = (((tid & 3) ^ ((sr >> 1) & 3))) * 8;       // swizzled global granule
  int soff = tid * 8;                                  // LINEAR LDS dest (halves)
  const __half* ga0 = A + (size_t)(row0 + sr) * lda + scg;
  const __half* ga1 = ga0 + (size_t)64 * lda;          // (sr+64)>>1&3 == sr>>1&3
  int gsw = ((lane >> 4) ^ ((lane >> 1) & 3)) * 8;     // swizzled read granule
  int aoff = (wm * 64 + (lane & 15)) * 32 + gsw;
  // B fragment pointers: row = output col (L2-hot weights), 64B-aligned rows
  const __half* gb0 = Bt + (size_t)(col0 + wn * 64 +  0 + (lane & 15)) * ldb + (lane >> 4) * 8;
  const __half* gb1 = Bt + (size_t)(col0 + wn * 64 + 16 + (lane & 15)) * ldb + (lane >> 4) * 8;
  const __half* gb2 = Bt + (size_t)(col0 + wn * 64 + 32 + (lane & 15)) * ldb + (lane >> 4) * 8;
  const __half* gb3 = Bt + (size_t)(col0 + wn * 64 + 48 + (lane & 15)) * ldb + (lane >> 4) * 8;

  if (STATS && tid < 128) { cs[tid] = 0.f; cq[tid] = 0.f; }

  floatx4 zero4 = {0.f, 0.f, 0.f, 0.f};
  floatx4 acc[4][4];
#pragma unroll
  for (int i = 0; i < 4; ++i)
#pragma unroll
    for (int j = 0; j < 4; ++j) acc[i][j] = zero4;

  half8 bf0[4], bf1[4];
  int nT = K >> 5;                       // 10 or 20 (even)
  // prologue: stage A tiles 0,1; prefetch bf(0)
  gload16(ga0, &As[0][soff]);
  gload16(ga1, &As[0][soff + 2048]);
  gload16(ga0 + 32, &As[1][soff]);
  gload16(ga1 + 32, &As[1][soff + 2048]);
  bf0[0] = *(const half8*)(gb0);
  bf0[1] = *(const half8*)(gb1);
  bf0[2] = *(const half8*)(gb2);
  bf0[3] = *(const half8*)(gb3);

  int cur = 0;
  int t = 0;
  for (; t + 1 < nT - 2; t += 2) {
    KSTEP(t,     cur, bf0, bf1, 1, 1, 12); cur = (cur == 2) ? 0 : cur + 1;
    KSTEP(t + 1, cur, bf1, bf0, 1, 1, 12); cur = (cur == 2) ? 0 : cur + 1;
  }
  KSTEP(nT - 2, cur, bf0, bf1, 0, 1, 10); cur = (cur == 2) ? 0 : cur + 1;
  KSTEP(nT - 1, cur, bf1, bf0, 0, 0, 4);

  // epilogue: C/D layout col=lane&15, row=quad*4+reg
  float ls[4] = {0.f, 0.f, 0.f, 0.f}, lq[4] = {0.f, 0.f, 0.f, 0.f};
#pragma unroll
  for (int mi = 0; mi < 4; ++mi) {
#pragma unroll
    for (int ni = 0; ni < 4; ++ni) {
      int col = col0 + wn * 64 + ni * 16 + (lane & 15);
      float bv = bias[col];
#pragma unroll
      for (int r = 0; r < 4; ++r) {
        int row = row0 + wm * 64 + mi * 16 + (lane >> 4) * 4 + r;
        float v = acc[mi][ni][r] + bv;
        if (RELU) v = fmaxf(v, 0.f);
        C[(size_t)row * ldc + col] = __float2half(v);
        if (STATS && row < N_NODES) { ls[ni] += v; lq[ni] += v * v; }
      }
    }
  }
  if (STATS) {
#pragma unroll
    for (int ni = 0; ni < 4; ++ni) {
      int ci = wn * 64 + ni * 16 + (lane & 15);
      atomicAdd(&cs[ci], ls[ni]);
      atomicAdd(&cq[ci], lq[ni]);
    }
    __syncthreads();
    int col = col0 + tid;
    if (tid < 128 && col < EMB) {
      atomicAdd(&stats[col], cs[tid]);
      atomicAdd(&stats[EMB + col], cq[tid]);
    }
  }
}

// ---------------- batchnorm apply (+relu), grid-stride half2 ----------------
__global__ __launch_bounds__(256)
void bn_kernel(const __half* __restrict__ h2, const float* __restrict__ stats,
               const float* __restrict__ gamma, const float* __restrict__ beta,
               __half* __restrict__ hout, float* __restrict__ fout, int relu) {
  const float invN = 1.0f / (float)N_NODES;
  const int total = N_NODES * 150;
  for (int i = blockIdx.x * 256 + threadIdx.x; i < total; i += gridDim.x * 256) {
    int node = i / 150;
    int c = (i - node * 150) * 2;
    float m0 = stats[c] * invN,      m1 = stats[c + 1] * invN;
    float v0 = stats[EMB + c] * invN - m0 * m0;
    float v1 = stats[EMB + c + 1] * invN - m1 * m1;
    float s0 = gamma[c] * rsqrtf(v0 + 1e-5f);
    float s1 = gamma[c + 1] * rsqrtf(v1 + 1e-5f);
    float t0 = beta[c] - m0 * s0, t1 = beta[c + 1] - m1 * s1;
    float2 u = __half22float2(*(const __half2*)&h2[(size_t)node * NP2 + c]);
    float r0 = u.x * s0 + t0, r1 = u.y * s1 + t1;
    if (relu) { r0 = fmaxf(r0, 0.f); r1 = fmaxf(r1, 0.f); }
    if (hout) {
      *(__half2*)&hout[(size_t)node * HSH + c] = __floats2half2_rn(r0, r1);
    } else {
      fout[(size_t)node * EMB + c]     = r0;
      fout[(size_t)node * EMB + c + 1] = r1;
    }
  }
}

extern "C" void kernel_launch(void* const* d_in, const int* in_sizes, int n_in,
                              void* d_out, int out_size, void* d_ws, size_t ws_size,
                              hipStream_t stream) {
  const int*   x      = (const int*)d_in[0];
  const int*   ei     = (const int*)d_in[1];
  const int*   ea     = (const int*)d_in[2];
  const float* x_emb1 = (const float*)d_in[3];
  const float* x_emb2 = (const float*)d_in[4];
  const float* edge1  = (const float*)d_in[5];
  const float* edge2  = (const float*)d_in[6];
  const float* W1     = (const float*)d_in[7];
  const float* b1     = (const float*)d_in[8];
  const float* W2     = (const float*)d_in[9];
  const float* b2     = (const float*)d_in[10];
  const float* gamma  = (const float*)d_in[11];
  const float* beta   = (const float*)d_in[12];
  float* out = (float*)d_out;

  char* ws = (char*)d_ws;
  size_t off = 0;
  auto nxt = [&](size_t bytes) {
    void* p = ws + off;
    off += (bytes + 255) & ~(size_t)255;
    return p;
  };
  // Region R: tbuf (fp16 [NPAD][NP1], live gemm1->gemm2) aliases hbuf
  // (fp16 [N_NODES][HSH], read only by aggregate, rewritten by bn).
  size_t tbuf_bytes = (size_t)NPAD * NP1 * 2;        // 38.5 MB
  size_t hbuf_bytes = (size_t)N_NODES * HSH * 2;     // 18.2 MB
  char* R = (char*)nxt(tbuf_bytes > hbuf_bytes ? tbuf_bytes : hbuf_bytes);
  __half* hbuf = (__half*)R;
  __half* tbuf = (__half*)R;
  // Region S: aggb (fp16 [NPAD][K1], live aggregate->gemm1) aliases h2
  // (fp16 [NPAD][NP2], live gemm2->bn).
  size_t agg_bytes = (size_t)NPAD * K1 * 2;          // 19.3 MB
  size_t h2_bytes  = (size_t)NPAD * NP2 * 2;         // 23.1 MB
  char* S = (char*)nxt(agg_bytes > h2_bytes ? agg_bytes : h2_bytes);
  __half* aggb = (__half*)S;
  __half* h2   = (__half*)S;
  __half* w1t  = (__half*)nxt((size_t)LAYERS * NP1 * K1 * 2);
  __half* w2t  = (__half*)nxt((size_t)LAYERS * NP2 * NP1 * 2);
  float*  b1p  = (float*)nxt((size_t)LAYERS * NP1 * 4);
  float*  b2p  = (float*)nxt((size_t)LAYERS * NP2 * 4);
  float*  stat = (float*)nxt((size_t)LAYERS * 2 * EMB * 4);
  int*    deg  = (int*)nxt((size_t)N_NODES * 4);
  int*    rptr = (int*)nxt((size_t)(N_NODES + 1) * 4);
  int*    curs = (int*)nxt((size_t)N_NODES * 4);
  int*    ebuf = (int*)nxt((size_t)N_EDGES * 4);
  // total ~68 MB

  prep_kernel<<<2048, 256, 0, stream>>>(W1, W2, b1, b2, x, x_emb1, x_emb2,
                                        w1t, w2t, b1p, b2p, hbuf, deg, stat);

  count_kernel<<<(N_EDGES + 255) / 256, 256, 0, stream>>>(ei, deg);
  scan_kernel<<<1, 1024, 0, stream>>>(deg, rptr, curs);
  fill_kernel<<<(N_EDGES + 255) / 256, 256, 0, stream>>>(ei, ea, curs, ebuf);

  for (int l = 0; l < LAYERS; ++l) {
    aggregate_kernel<<<NPAD / 4, 256, 0, stream>>>(
        hbuf, rptr, ebuf, edge1 + (size_t)l * 6 * EMB, edge2 + (size_t)l * 3 * EMB, aggb);
    gemm_kernel<1, 0><<<dim3(NP1 / 128, NPAD / 128), 256, 0, stream>>>(
        aggb, K1, w1t + (size_t)l * NP1 * K1, K1, b1p + l * NP1, tbuf, NP1, K1, nullptr);
    gemm_kernel<0, 1><<<dim3(NP2 / 128, NPAD / 128), 256, 0, stream>>>(
        tbuf, NP1, w2t + (size_t)l * NP2 * NP1, NP1, b2p + l * NP2, h2, NP2, NP1,
        stat + l * 2 * EMB);
    bn_kernel<<<1024, 256, 0, stream>>>(
        h2, stat + l * 2 * EMB, gamma + l * EMB, beta + l * EMB,
        (l < LAYERS - 1) ? hbuf : (__half*)nullptr,
        (l < LAYERS - 1) ? (float*)nullptr : out,
        (l < LAYERS - 1) ? 1 : 0);
  }
}